// Round 1
// baseline (58.246 us; speedup 1.0000x reference)
//
#include <hip/hip_runtime.h>
#include <math.h>

// RBF quadrature: out[0][m][n] = sum_k w_k / (1 + 4pi^2 ex^2)
//                 out[1][m][n] = -2pi * sum_k w_k * ex / (1 + 4pi^2 ex^2)
//   ex = exp(log f_m + log_t_n + y_k),  y = linspace(-50,50,500)
//   w_k = exp(-y_k^2) * dy
//
// Numerics: w_k underflows to exactly 0 in fp32 for |y_k| > ~10.16, i.e.
// only k in [199,300] contribute. We loop k in [K0,K1)=[192,308): 116 points
// (multiple of 4 for unrolling); the pad points have w==0 exactly.

#define NY   500
#define K0   192
#define K1   308
#define NK   (K1 - K0)   // 116

__global__ __launch_bounds__(256) void rbf_kernel(
        const float* __restrict__ f_vec,
        const float* __restrict__ log_t,
        float* __restrict__ out,
        int F, int T) {
    __shared__ float sW[NK];   // w_k = exp(-y^2)*dy
    __shared__ float sE[NK];   // exp(y_k)

    const float dy = 100.0f / 499.0f;

    // Stage quadrature weights into LDS (cooperative, once per block)
    for (int k = threadIdx.x; k < NK; k += blockDim.x) {
        float y = -50.0f + (float)(k + K0) * dy;
        sW[k] = expf(-y * y) * dy;     // exact 0 outside the true support
        sE[k] = expf(y);
    }
    __syncthreads();

    const int m = blockIdx.x;
    const float lf = logf(f_vec[m]);
    const float c = 4.0f * (float)M_PI * (float)M_PI;

    for (int n = threadIdx.x; n < T; n += blockDim.x) {
        const float e0 = expf(lf + log_t[n]);   // exp(s_mn)

        float re = 0.0f, im = 0.0f;
        #pragma unroll 4
        for (int k = 0; k < NK; ++k) {
            float ex = e0 * sE[k];                              // exp(s+y_k)
            float denom = fmaf(c * ex, ex, 1.0f);               // 1 + 4pi^2 ex^2
            float r = __builtin_amdgcn_rcpf(denom);             // v_rcp_f32, ~1ulp
            float wr = sW[k] * r;
            re += wr;                                           // w/denom
            im = fmaf(wr, ex, im);                              // w*ex/denom
        }

        const int idx = m * T + n;
        out[idx]         = re;
        out[F * T + idx] = im * (-2.0f * (float)M_PI);
    }
}

extern "C" void kernel_launch(void* const* d_in, const int* in_sizes, int n_in,
                              void* d_out, int out_size, void* d_ws, size_t ws_size,
                              hipStream_t stream) {
    const float* f_vec = (const float*)d_in[0];
    const float* log_t = (const float*)d_in[1];
    float* out = (float*)d_out;
    const int F = in_sizes[0];   // 512
    const int T = in_sizes[1];   // 256

    rbf_kernel<<<dim3(F), dim3(256), 0, stream>>>(f_vec, log_t, out, F, T);
}

// Round 2
// 55.706 us; speedup vs baseline: 1.0456x; 1.0456x over previous
//
#include <hip/hip_runtime.h>
#include <math.h>

// RBF quadrature: out[0][m][n] = sum_k w_k / (1 + 4pi^2 ex^2)
//                 out[1][m][n] = -2pi * sum_k w_k * ex / (1 + 4pi^2 ex^2)
//   ex = exp(log f_m + log_t_n + y_k),  y = linspace(-50,50,500), w = exp(-y^2)*dy
//
// Window: w_k's Gaussian mass outside |y|<=3.106 (k in [234,266)) is
// sqrt(pi)*erfc(3.1) ~ 2e-5 -- 3 orders below the 3.5e-2 threshold (we
// measured absmax 0.0078 with the full 116-pt support). 32 points.
//
// Factorization: ex = e0*E_k with e0 = exp(lf+lt) per thread, E_k = exp(y_k).
//   denom = 1 + (4pi^2 e0^2) * E_k^2 = fma(u, g_k, 1)
//   re   += w_k * rcp(denom)
//   ai   += (w_k*E_k) * rcp(denom);  im = -2pi * e0 * ai
// Inner loop = 3 fma + 1 v_rcp_f32 per k, constants preloaded to VGPRs.

#define K0 234
#define NK 32

__global__ __launch_bounds__(256) void rbf_kernel(
        const float* __restrict__ f_vec,
        const float* __restrict__ log_t,
        float* __restrict__ out,
        int F, int T) {
    __shared__ float sW[NK], sG[NK], sH[NK];

    const float dy = 100.0f / 499.0f;

    if (threadIdx.x < NK) {
        const int k = threadIdx.x;
        const float y = -50.0f + (float)(k + K0) * dy;
        const float w = expf(-y * y) * dy;
        const float e = expf(y);
        sW[k] = w;          // w_k
        sG[k] = e * e;      // E_k^2
        sH[k] = w * e;      // w_k * E_k
    }
    __syncthreads();

    // Preload quadrature constants into registers (broadcast LDS reads,
    // compiler merges to ds_read_b128; ~96 VGPRs).
    float w[NK], g[NK], h[NK];
    #pragma unroll
    for (int k = 0; k < NK; ++k) { w[k] = sW[k]; g[k] = sG[k]; h[k] = sH[k]; }

    const int m = blockIdx.x;
    const float lf = logf(f_vec[m]);
    const float c = 4.0f * (float)M_PI * (float)M_PI;

    for (int n = threadIdx.x; n < T; n += blockDim.x) {
        const float e0 = expf(lf + log_t[n]);
        const float u  = c * e0 * e0;

        float re = 0.0f, ai = 0.0f;
        #pragma unroll
        for (int k = 0; k < NK; ++k) {
            const float denom = fmaf(u, g[k], 1.0f);
            const float r = __builtin_amdgcn_rcpf(denom);   // v_rcp_f32
            re = fmaf(w[k], r, re);
            ai = fmaf(h[k], r, ai);
        }

        const int idx = m * T + n;
        out[idx]         = re;
        out[F * T + idx] = ai * e0 * (-2.0f * (float)M_PI);
    }
}

extern "C" void kernel_launch(void* const* d_in, const int* in_sizes, int n_in,
                              void* d_out, int out_size, void* d_ws, size_t ws_size,
                              hipStream_t stream) {
    const float* f_vec = (const float*)d_in[0];
    const float* log_t = (const float*)d_in[1];
    float* out = (float*)d_out;
    const int F = in_sizes[0];   // 512
    const int T = in_sizes[1];   // 256

    rbf_kernel<<<dim3(F), dim3(256), 0, stream>>>(f_vec, log_t, out, F, T);
}